// Round 16
// baseline (1197.045 us; speedup 1.0000x reference)
//
#include <hip/hip_runtime.h>

#define COL_DIM 4096
#define ROW_DIM 1024
#define NUM_LAYERS 3
#define KNN_E 16384
#define GENET_E 131072

typedef __attribute__((ext_vector_type(8))) short short8;
typedef __attribute__((ext_vector_type(4))) float f32x4;
typedef __attribute__((ext_vector_type(16))) float f32x16;

// ---------------- fp32 -> bf16 hi/lo helpers ----------------
__device__ inline unsigned short f2bf(float f) {
  unsigned int u = __float_as_uint(f);
  u += 0x7FFFu + ((u >> 16) & 1u); // RNE
  return (unsigned short)(u >> 16);
}
__device__ inline float bf2f(unsigned short h) {
  return __uint_as_float(((unsigned int)h) << 16);
}
// packed HW convert: dst.lo16 = bf16(a), dst.hi16 = bf16(b)
__device__ inline unsigned int cvtpk(float a, float b) {
  unsigned int r;
  asm("v_cvt_pk_bf16_f32 %0, %1, %2" : "=v"(r) : "v"(a), "v"(b));
  return r;
}
// 8 floats -> hi short8 + lo short8. Self-correcting: lo from ACTUAL hi.
__device__ inline void cvt_f4pair(float4 a4, float4 b4, short8& h, short8& l) {
  float f[8] = {a4.x, a4.y, a4.z, a4.w, b4.x, b4.y, b4.z, b4.w};
  union { unsigned int u[4]; short8 s; } H, L;
#pragma unroll
  for (int w = 0; w < 4; w++) {
    float a = f[2 * w], b = f[2 * w + 1];
    unsigned int hw = cvtpk(a, b);
    float ah = __uint_as_float(hw << 16);
    float bh = __uint_as_float(hw & 0xffff0000u);
    H.u[w] = hw;
    L.u[w] = cvtpk(a - ah, b - bh);
  }
  h = H.s;
  l = L.s;
}

// ---------------- transpose + split: in[R][C] -> outf/outh/outl [C][R] --------
__global__ void transpose_split_kernel(const float* __restrict__ in,
                                       float* __restrict__ outf,
                                       unsigned short* __restrict__ outh,
                                       unsigned short* __restrict__ outl,
                                       int R, int C) {
  __shared__ float tile[32][33];
  int c0 = blockIdx.x * 32, r0 = blockIdx.y * 32;
  int tx = threadIdx.x, ty = threadIdx.y; // 32 x 8
#pragma unroll
  for (int i = 0; i < 32; i += 8)
    tile[ty + i][tx] = in[(size_t)(r0 + ty + i) * C + c0 + tx];
  __syncthreads();
#pragma unroll
  for (int i = 0; i < 32; i += 8) {
    float v = tile[tx][ty + i];
    size_t o = (size_t)(c0 + ty + i) * R + r0 + tx;
    outf[o] = v;
    unsigned short h = f2bf(v);
    outh[o] = h;
    outl[o] = f2bf(v - bf2f(h));
  }
}

// ---------------- CSR build ----------------
__global__ void count_kernel(const int* __restrict__ dst, int E, int* __restrict__ cnt) {
  int e = blockIdx.x * 256 + threadIdx.x;
  if (e < E) atomicAdd(&cnt[dst[e]], 1);
}

__global__ void scan_kernel(const int* __restrict__ cnt, int* __restrict__ indptr, int n) {
  __shared__ int s[1024];
  __shared__ int base_s;
  int tid = threadIdx.x;
  if (tid == 0) { base_s = 0; indptr[0] = 0; }
  __syncthreads();
  for (int c = 0; c < n; c += 1024) {
    int i = c + tid;
    int v = (i < n) ? cnt[i] : 0;
    s[tid] = v;
    __syncthreads();
    for (int off = 1; off < 1024; off <<= 1) {
      int t = (tid >= off) ? s[tid - off] : 0;
      __syncthreads();
      s[tid] += t;
      __syncthreads();
    }
    if (i < n) indptr[i + 1] = base_s + s[tid];
    __syncthreads();
    if (tid == 0) base_s += s[1023];
    __syncthreads();
  }
}

__global__ void copy_int_kernel(const int* __restrict__ a, int* __restrict__ b, int n) {
  int i = blockIdx.x * 256 + threadIdx.x;
  if (i < n) b[i] = a[i];
}

__global__ void fill_kernel(const int* __restrict__ src, const int* __restrict__ dst, int E,
                            int* __restrict__ cursor, int* __restrict__ idx) {
  int e = blockIdx.x * 256 + threadIdx.x;
  if (e < E) {
    int p = atomicAdd(&cursor[dst[e]], 1);
    idx[p] = src[e];
  }
}

// ---------------- wave-per-bucket rank sort (deterministic: sorted by value) ---
__global__ void rank_sort_kernel(const int* __restrict__ indptr, int* __restrict__ idx,
                                 int n) {
  int wv = threadIdx.x >> 6, lane = threadIdx.x & 63;
  int b = blockIdx.x * (blockDim.x >> 6) + wv;
  if (b >= n) return;
  int lo = indptr[b];
  int d = indptr[b + 1] - lo;
  if (d <= 1) return;
  if (d <= 256) {
    int v0 = (lane < d) ? idx[lo + lane] : 0x7fffffff;
    int v1 = (64 + lane < d) ? idx[lo + 64 + lane] : 0x7fffffff;
    int v2 = (128 + lane < d) ? idx[lo + 128 + lane] : 0x7fffffff;
    int v3 = (192 + lane < d) ? idx[lo + 192 + lane] : 0x7fffffff;
    int r0 = 0, r1 = 0, r2 = 0, r3 = 0;
    for (int j = 0; j < d; j++) {
      int q = j >> 6;
      int sel = (q == 0) ? v0 : (q == 1) ? v1 : (q == 2) ? v2 : v3;
      int bj = __shfl(sel, j & 63);
      r0 += (bj < v0 || (bj == v0 && j < lane)) ? 1 : 0;
      r1 += (bj < v1 || (bj == v1 && j < 64 + lane)) ? 1 : 0;
      r2 += (bj < v2 || (bj == v2 && j < 128 + lane)) ? 1 : 0;
      r3 += (bj < v3 || (bj == v3 && j < 192 + lane)) ? 1 : 0;
    }
    if (lane < d) idx[lo + r0] = v0;
    if (64 + lane < d) idx[lo + r1] = v1;
    if (128 + lane < d) idx[lo + r2] = v2;
    if (192 + lane < d) idx[lo + r3] = v3;
  } else if (lane == 0) {
    for (int i = lo + 1; i < lo + d; i++) {
      int v = idx[i];
      int j = i - 1;
      while (j >= lo && idx[j] > v) { idx[j + 1] = idx[j]; j--; }
      idx[j + 1] = v;
    }
  }
}

// ---------------- neighbor mean, XCD-sliced, + split to bf16 hi/lo ------------
__global__ void agg_slice_kernel(const float* __restrict__ src,
                                 unsigned short* __restrict__ dh,
                                 unsigned short* __restrict__ dl,
                                 const int* __restrict__ indptr,
                                 const int* __restrict__ idx, int D, int tprsh) {
  int tid = threadIdx.x;
  int d = blockIdx.y * (256 >> tprsh) + (tid >> tprsh);
  int k4 = blockIdx.x * (1 << tprsh) + (tid & ((1 << tprsh) - 1));
  int lo = indptr[d], hi = indptr[d + 1];
  float4 s = make_float4(0.f, 0.f, 0.f, 0.f);
  for (int j = lo; j < hi; j++) {
    float4 v = ((const float4*)(src + (size_t)idx[j] * D))[k4];
    s.x += v.x; s.y += v.y; s.z += v.z; s.w += v.w;
  }
  int c = hi - lo;
  float inv = 1.f / (float)(c > 0 ? c : 1);
  s.x *= inv; s.y *= inv; s.z *= inv; s.w *= inv;
  ushort4 h, l;
  h.x = f2bf(s.x); l.x = f2bf(s.x - bf2f(h.x));
  h.y = f2bf(s.y); l.y = f2bf(s.y - bf2f(h.y));
  h.z = f2bf(s.z); l.z = f2bf(s.z - bf2f(h.z));
  h.w = f2bf(s.w); l.w = f2bf(s.w - bf2f(h.w));
  ((ushort4*)(dh + (size_t)d * D))[k4] = h;
  ((ushort4*)(dl + (size_t)d * D))[k4] = l;
}

// ---------------- dual split-bf16 x3 MFMA NT GEMM (r8 structure, 32x32x16) -----
// P_kh[m][n] = sum_k Op(kh,A)[m,k] * Op(kh,B)[n,k]; kh = bid>>8 selects the
// (A1,B1) or (A2,B2) product. AF32=1: A-side fp32 staged raw, cvtpk'd in-reg.
// 256 thr = 4 waves, 128x128 tile, wave tile 64x64 = 2x2 frags of 32x32.
// MFMA: v_mfma_f32_32x32x16_bf16 (4061 FLOP/cyc vs 3378 for 16x16x32; 24 vs 48
// instr per wave-tile). A/B frag: row/col = lane&31, k = (lane>>5)*8+e.
// C/D: col=lane&31, row=(reg&3)+8*(reg>>2)+4*(lane>>5) [m74/m101-verified].
// Staging, swizzles, 2-buf ring + counted vmcnt(8) identical to r8.
#define GBM 128
#define GBN 128
#define GBK 32

#define GLDS(g, l)                                                             \
  __builtin_amdgcn_global_load_lds(                                            \
      (const __attribute__((address_space(1))) void*)(g),                      \
      (__attribute__((address_space(3))) void*)(l), 16, 0, 0)

#define BAR()                                                                  \
  {                                                                            \
    asm volatile("" ::: "memory");                                             \
    __builtin_amdgcn_s_barrier();                                              \
    asm volatile("" ::: "memory");                                             \
  }

template <int AF32>
__global__ __launch_bounds__(256, 2) void dual_gemm_kernel(
    const float* __restrict__ Af1, const float* __restrict__ Af2,
    const unsigned short* __restrict__ Ah1, const unsigned short* __restrict__ Al1,
    const unsigned short* __restrict__ Ah2, const unsigned short* __restrict__ Al2,
    const float* __restrict__ Bf1, const float* __restrict__ Bf2,
    const unsigned short* __restrict__ Bh1, const unsigned short* __restrict__ Bl1,
    const unsigned short* __restrict__ Bh2, const unsigned short* __restrict__ Bl2,
    float* __restrict__ P0, float* __restrict__ P1, int Kloc) {
  // per buffer 32KB: [0,16K) = fp32 region base FB, [16K,32K) = bf16 h/l.
  __shared__ char smraw[2][32768];
  const int tid = threadIdx.x;
  const int lane = tid & 63;
  const int wid = tid >> 6;
  const int wr = wid >> 1, wc = wid & 1;

  const int bid = blockIdx.x;
  const int kh = bid >> 8;
  const int tile = bid & 255;
  const int swz = (tile & 7) * 32 + (tile >> 3); // XCD-chunked
  const int bm0 = (swz >> 3) * GBM;
  const int bn0 = (swz & 7) * GBN;

  // staging geometry (identical to r8). fp32 operand: 1024 units of 16B,
  // 4/thread, row = 8 units, source slot = (q ^ (r&7)). bf16 operand: 512
  // units per h/l, 2/thread, row = 4 units, source slot = (q ^ ((r>>1)&3)).
  const int u0 = tid, u1 = tid + 256, u2 = tid + 512, u3 = tid + 768;
  const int fr0 = u0 >> 3, fr1 = u1 >> 3, fr2 = u2 >> 3, fr3 = u3 >> 3;
  const int fc0 = ((u0 & 7) ^ (fr0 & 7)) * 4;
  const int fc1 = ((u1 & 7) ^ (fr1 & 7)) * 4;
  const int fc2 = ((u2 & 7) ^ (fr2 & 7)) * 4;
  const int fc3 = ((u3 & 7) ^ (fr3 & 7)) * 4;
  const int hr0 = u0 >> 2, hr1 = u1 >> 2;
  const int hc0 = ((u0 & 3) ^ ((hr0 >> 1) & 3)) * 8;
  const int hc1 = ((u1 & 3) ^ ((hr1 >> 1) & 3)) * 8;

  const float* gF0; const float* gF1; const float* gF2; const float* gF3;
  const unsigned short* gH0; const unsigned short* gH1;
  const unsigned short* gL0; const unsigned short* gL1;
  if constexpr (AF32) {
    const float* Af = kh ? Af2 : Af1;
    const unsigned short* Bh = kh ? Bh2 : Bh1;
    const unsigned short* Bl = kh ? Bl2 : Bl1;
    gF0 = Af + (size_t)(bm0 + fr0) * Kloc + fc0;
    gF1 = Af + (size_t)(bm0 + fr1) * Kloc + fc1;
    gF2 = Af + (size_t)(bm0 + fr2) * Kloc + fc2;
    gF3 = Af + (size_t)(bm0 + fr3) * Kloc + fc3;
    gH0 = Bh + (size_t)(bn0 + hr0) * Kloc + hc0;
    gH1 = Bh + (size_t)(bn0 + hr1) * Kloc + hc1;
    gL0 = Bl + (size_t)(bn0 + hr0) * Kloc + hc0;
    gL1 = Bl + (size_t)(bn0 + hr1) * Kloc + hc1;
  } else {
    const unsigned short* Ah = kh ? Ah2 : Ah1;
    const unsigned short* Al = kh ? Al2 : Al1;
    const float* Bf = kh ? Bf2 : Bf1;
    gH0 = Ah + (size_t)(bm0 + hr0) * Kloc + hc0;
    gH1 = Ah + (size_t)(bm0 + hr1) * Kloc + hc1;
    gL0 = Al + (size_t)(bm0 + hr0) * Kloc + hc0;
    gL1 = Al + (size_t)(bm0 + hr1) * Kloc + hc1;
    gF0 = Bf + (size_t)(bn0 + fr0) * Kloc + fc0;
    gF1 = Bf + (size_t)(bn0 + fr1) * Kloc + fc1;
    gF2 = Bf + (size_t)(bn0 + fr2) * Kloc + fc2;
    gF3 = Bf + (size_t)(bn0 + fr3) * Kloc + fc3;
  }
  const int FB = AF32 ? 0 : 16384;      // byte base of fp32 region
  const int HB = AF32 ? 16384 : 0;      // byte base of bf16 h region

  // always exactly 8 GLDS per STAGE (vmcnt counting depends on it)
  auto STAGE = [&](int buf) {
    char* base = &smraw[buf][0];
    GLDS(gF0, base + FB + u0 * 16); GLDS(gF1, base + FB + u1 * 16);
    GLDS(gF2, base + FB + u2 * 16); GLDS(gF3, base + FB + u3 * 16);
    GLDS(gH0, base + HB + u0 * 16); GLDS(gH1, base + HB + u1 * 16);
    GLDS(gL0, base + HB + 8192 + u0 * 16); GLDS(gL1, base + HB + 8192 + u1 * 16);
    gF0 += GBK; gF1 += GBK; gF2 += GBK; gF3 += GBK;
    gH0 += GBK; gH1 += GBK; gL0 += GBK; gL1 += GBK;
  };

  // fragment ds_read offsets (32x32 frags)
  const int l31 = lane & 31;
  const int khi = lane >> 5; // 0/1 -> k = khi*8 + e within a 16-k step
  // fp32 side: frag fm, kstep ks: row rA = FROWb + fm*32; slots s0=ks*4+khi*2,
  // s0+1; physical = s ^ (rA&7); float units.
  const int FROWb = (AF32 ? wr : wc) * 64 + l31;
  int offF32[2][2][2];
  // bf16 side: frag fn, kstep ks: row rB = HROWb + fn*32; logical slot
  // s=ks*2+khi; physical = s ^ ((rB>>1)&3); ushort units.
  const int HROWb = (AF32 ? wc : wr) * 64 + l31;
  int offH32[2][2];
#pragma unroll
  for (int f = 0; f < 2; f++) {
#pragma unroll
    for (int ks = 0; ks < 2; ks++) {
      int rA = FROWb + f * 32;
      int s0 = ks * 4 + khi * 2;
      offF32[f][ks][0] = rA * 32 + ((s0 ^ (rA & 7)) * 4);
      offF32[f][ks][1] = rA * 32 + (((s0 + 1) ^ (rA & 7)) * 4);
      int rB = HROWb + f * 32;
      offH32[f][ks] = rB * 32 + (((ks * 2 + khi) ^ ((rB >> 1) & 3)) * 8);
    }
  }

  f32x16 acc[2][2];
#pragma unroll
  for (int i = 0; i < 2; i++)
#pragma unroll
    for (int j = 0; j < 2; j++) acc[i][j] = (f32x16)(0.f);

  const int nt = Kloc / GBK;
  STAGE(0);
  STAGE(1);
  int cur = 0;
  for (int t = 0; t < nt; t++) {
    if (t < nt - 1) {
      asm volatile("s_waitcnt vmcnt(8)" ::: "memory"); // tile t landed
    } else {
      asm volatile("s_waitcnt vmcnt(0)" ::: "memory");
    }
    BAR();
    const float* smF = (const float*)&smraw[cur][FB];
    const unsigned short* smH = (const unsigned short*)&smraw[cur][HB];
    const unsigned short* smL = smH + 4096;
    short8 rdh[2][2], rdl[2][2], ch[2][2], cl[2][2];
#pragma unroll
    for (int f = 0; f < 2; f++) {
#pragma unroll
      for (int ks = 0; ks < 2; ks++) {
        rdh[f][ks] = *(const short8*)&smH[offH32[f][ks]];
        rdl[f][ks] = *(const short8*)&smL[offH32[f][ks]];
        float4 a = *(const float4*)&smF[offF32[f][ks][0]];
        float4 b = *(const float4*)&smF[offF32[f][ks][1]];
        cvt_f4pair(a, b, ch[f][ks], cl[f][ks]);
      }
    }
    __builtin_amdgcn_s_setprio(1);
    if constexpr (AF32) {
      // A = weights (ch/cl, m-side), B = activations (rdh/rdl, n-side)
#pragma unroll
      for (int ks = 0; ks < 2; ks++)
#pragma unroll
        for (int fm = 0; fm < 2; fm++)
#pragma unroll
          for (int fn = 0; fn < 2; fn++)
            acc[fm][fn] = __builtin_amdgcn_mfma_f32_32x32x16_bf16(
                ch[fm][ks], rdh[fn][ks], acc[fm][fn], 0, 0, 0);
#pragma unroll
      for (int ks = 0; ks < 2; ks++)
#pragma unroll
        for (int fm = 0; fm < 2; fm++)
#pragma unroll
          for (int fn = 0; fn < 2; fn++)
            acc[fm][fn] = __builtin_amdgcn_mfma_f32_32x32x16_bf16(
                ch[fm][ks], rdl[fn][ks], acc[fm][fn], 0, 0, 0);
#pragma unroll
      for (int ks = 0; ks < 2; ks++)
#pragma unroll
        for (int fm = 0; fm < 2; fm++)
#pragma unroll
          for (int fn = 0; fn < 2; fn++)
            acc[fm][fn] = __builtin_amdgcn_mfma_f32_32x32x16_bf16(
                cl[fm][ks], rdh[fn][ks], acc[fm][fn], 0, 0, 0);
    } else {
      // A = activations (rdh/rdl, m-side), B = weights (ch/cl, n-side)
#pragma unroll
      for (int ks = 0; ks < 2; ks++)
#pragma unroll
        for (int fm = 0; fm < 2; fm++)
#pragma unroll
          for (int fn = 0; fn < 2; fn++)
            acc[fm][fn] = __builtin_amdgcn_mfma_f32_32x32x16_bf16(
                rdh[fm][ks], ch[fn][ks], acc[fm][fn], 0, 0, 0);
#pragma unroll
      for (int ks = 0; ks < 2; ks++)
#pragma unroll
        for (int fm = 0; fm < 2; fm++)
#pragma unroll
          for (int fn = 0; fn < 2; fn++)
            acc[fm][fn] = __builtin_amdgcn_mfma_f32_32x32x16_bf16(
                rdh[fm][ks], cl[fn][ks], acc[fm][fn], 0, 0, 0);
#pragma unroll
      for (int ks = 0; ks < 2; ks++)
#pragma unroll
        for (int fm = 0; fm < 2; fm++)
#pragma unroll
          for (int fn = 0; fn < 2; fn++)
            acc[fm][fn] = __builtin_amdgcn_mfma_f32_32x32x16_bf16(
                rdl[fm][ks], ch[fn][ks], acc[fm][fn], 0, 0, 0);
    }
    __builtin_amdgcn_s_setprio(0);
    BAR(); // all waves done reading sm[cur]
    if (t + 2 < nt) STAGE(cur);
    cur ^= 1;
  }

  float* P = kh ? P1 : P0;
#pragma unroll
  for (int fm = 0; fm < 2; fm++) {
#pragma unroll
    for (int fn = 0; fn < 2; fn++) {
#pragma unroll
      for (int reg = 0; reg < 16; reg++) {
        int row = bm0 + wr * 64 + fm * 32 + (reg & 3) + 8 * (reg >> 2) + 4 * khi;
        int col = bn0 + wc * 64 + fn * 32 + l31;
        P[(size_t)row * 1024 + col] = acc[fm][fn][reg];
      }
    }
  }
}

// ---------------- combine: C = leaky(P0+P1 + bias[row]) + hi/lo split ----------
__global__ void combine_split_kernel(const float* __restrict__ P0, const float* __restrict__ P1,
                                     const float* __restrict__ bias, float* __restrict__ Cf,
                                     unsigned short* __restrict__ Ch,
                                     unsigned short* __restrict__ Cl) {
  int i = blockIdx.x * 256 + threadIdx.x; // float4 index, 1M total
  float4 a = ((const float4*)P0)[i];
  float4 b = ((const float4*)P1)[i];
  float bb = bias[(i * 4) >> 10];
  float4 v;
  v.x = a.x + b.x + bb;
  v.y = a.y + b.y + bb;
  v.z = a.z + b.z + bb;
  v.w = a.w + b.w + bb;
  v.x = v.x > 0.f ? v.x : 0.01f * v.x;
  v.y = v.y > 0.f ? v.y : 0.01f * v.y;
  v.z = v.z > 0.f ? v.z : 0.01f * v.z;
  v.w = v.w > 0.f ? v.w : 0.01f * v.w;
  ((float4*)Cf)[i] = v;
  ushort4 h, l;
  h.x = f2bf(v.x); l.x = f2bf(v.x - bf2f(h.x));
  h.y = f2bf(v.y); l.y = f2bf(v.y - bf2f(h.y));
  h.z = f2bf(v.z); l.z = f2bf(v.z - bf2f(h.z));
  h.w = f2bf(v.w); l.w = f2bf(v.w - bf2f(h.w));
  ((ushort4*)Ch)[i] = h;
  ((ushort4*)Cl)[i] = l;
}

// ---------------- combine: C = leaky(P0+P1 + bias[col]) ----------------
__global__ void combine_kernel(const float* __restrict__ P0, const float* __restrict__ P1,
                               const float* __restrict__ bias, float* __restrict__ C) {
  int i = blockIdx.x * 256 + threadIdx.x;
  float4 a = ((const float4*)P0)[i];
  float4 b = ((const float4*)P1)[i];
  float4 bb = *(const float4*)(bias + ((i * 4) & 1023));
  float4 v;
  v.x = a.x + b.x + bb.x;
  v.y = a.y + b.y + bb.y;
  v.z = a.z + b.z + bb.z;
  v.w = a.w + b.w + bb.w;
  v.x = v.x > 0.f ? v.x : 0.01f * v.x;
  v.y = v.y > 0.f ? v.y : 0.01f * v.y;
  v.z = v.z > 0.f ? v.z : 0.01f * v.z;
  v.w = v.w > 0.f ? v.w : 0.01f * v.w;
  ((float4*)C)[i] = v;
}

extern "C" void kernel_launch(void* const* d_in, const int* in_sizes, int n_in,
                              void* d_out, int out_size, void* d_ws, size_t ws_size,
                              hipStream_t stream) {
  const float* x      = (const float*)d_in[0];
  const float* col_Wl = (const float*)d_in[1];
  const float* col_Wr = (const float*)d_in[2];
  const float* col_b  = (const float*)d_in[3];
  const float* row_Wl = (const float*)d_in[4];
  const float* row_Wr = (const float*)d_in[5];
  const float* row_b  = (const float*)d_in[6];
  const int*   knn    = (const int*)d_in[7];   // [2][KNN_E]
  const int*   genet  = (const int*)d_in[8];   // [2][GENET_E]
  float* out = (float*)d_out;

  const size_t MAT = (size_t)COL_DIM * ROW_DIM; // 4M elements
  char* w = (char*)d_ws;
  float* ET  = (float*)w; w += MAT * 4;                   // [1024][4096]
  float* E1  = (float*)w; w += MAT * 4;                   // [4096][1024]
  unsigned short* ETh = (unsigned short*)w; w += MAT * 2;
  unsigned short* ETl = (unsigned short*)w; w += MAT * 2;
  unsigned short* Mh  = (unsigned short*)w; w += MAT * 2; // knn mean [1024][4096]
  unsigned short* Ml  = (unsigned short*)w; w += MAT * 2;
  unsigned short* Gh  = (unsigned short*)w; w += MAT * 2; // genet mean [4096][1024]
  unsigned short* Gl  = (unsigned short*)w; w += MAT * 2;
  unsigned short* E1h = (unsigned short*)w; w += MAT * 2;
  unsigned short* E1l = (unsigned short*)w; w += MAT * 2;
  float* PP0 = (float*)w; w += MAT * 4;
  float* PP1 = (float*)w; w += MAT * 4;
  int* kcnt = (int*)w; w += 1024 * 4;
  int* kptr = (int*)w; w += 1025 * 4;
  int* kidx = (int*)w; w += KNN_E * 4;
  int* gcnt = (int*)w; w += 4096 * 4;
  int* gptr = (int*)w; w += 4097 * 4;
  int* gidx = (int*)w; w += (size_t)GENET_E * 4;

  // ---- CSR build (deterministic via per-bucket value sort) ----
  hipMemsetAsync(kcnt, 0, 1024 * 4, stream);
  hipMemsetAsync(gcnt, 0, 4096 * 4, stream);
  count_kernel<<<KNN_E / 256, 256, 0, stream>>>(knn + KNN_E, KNN_E, kcnt);
  count_kernel<<<GENET_E / 256, 256, 0, stream>>>(genet + GENET_E, GENET_E, gcnt);
  scan_kernel<<<1, 1024, 0, stream>>>(kcnt, kptr, 1024);
  scan_kernel<<<1, 1024, 0, stream>>>(gcnt, gptr, 4096);
  copy_int_kernel<<<4, 256, 0, stream>>>(kptr, kcnt, 1024);
  copy_int_kernel<<<16, 256, 0, stream>>>(gptr, gcnt, 4096);
  fill_kernel<<<KNN_E / 256, 256, 0, stream>>>(knn, knn + KNN_E, KNN_E, kcnt, kidx);
  fill_kernel<<<GENET_E / 256, 256, 0, stream>>>(genet, genet + GENET_E, GENET_E, gcnt, gidx);
  rank_sort_kernel<<<256, 256, 0, stream>>>(kptr, kidx, 1024);
  rank_sort_kernel<<<1024, 256, 0, stream>>>(gptr, gidx, 4096);

  const float* Ein = x;
  for (int i = 0; i < NUM_LAYERS; i++) {
    const float* cWl = col_Wl + (size_t)i * COL_DIM * COL_DIM;
    const float* cWr = col_Wr + (size_t)i * COL_DIM * COL_DIM;
    const float* cb  = col_b + (size_t)i * COL_DIM;
    const float* rWl = row_Wl + (size_t)i * ROW_DIM * ROW_DIM;
    const float* rWr = row_Wr + (size_t)i * ROW_DIM * ROW_DIM;
    const float* rb  = row_b + (size_t)i * ROW_DIM;

    // ---- column branch: E1 = leaky(cWl@M^T + cWr@ET^T + cb[row]) ----
    transpose_split_kernel<<<dim3(ROW_DIM / 32, COL_DIM / 32), dim3(32, 8), 0, stream>>>(
        Ein, ET, ETh, ETl, COL_DIM, ROW_DIM);
    agg_slice_kernel<<<dim3(8, 512), 256, 0, stream>>>(ET, Mh, Ml, kptr, kidx,
                                                       COL_DIM, 7);
    dual_gemm_kernel<1><<<512, 256, 0, stream>>>(
        cWl, cWr, nullptr, nullptr, nullptr, nullptr,
        nullptr, nullptr, Mh, Ml, ETh, ETl, PP0, PP1, COL_DIM);
    combine_split_kernel<<<4096, 256, 0, stream>>>(PP0, PP1, cb, E1, E1h, E1l);

    // ---- row branch: out = leaky(G@rWl^T + E1@rWr^T + rb[col]) ----
    agg_slice_kernel<<<dim3(8, 512), 256, 0, stream>>>(E1, Gh, Gl, gptr, gidx,
                                                       ROW_DIM, 5);
    dual_gemm_kernel<0><<<512, 256, 0, stream>>>(
        nullptr, nullptr, Gh, Gl, E1h, E1l,
        rWl, rWr, nullptr, nullptr, nullptr, nullptr, PP0, PP1, ROW_DIM);
    combine_kernel<<<4096, 256, 0, stream>>>(PP0, PP1, rb, out);

    Ein = out;
  }
}

// Round 18
// 886.725 us; speedup vs baseline: 1.3500x; 1.3500x over previous
//
#include <hip/hip_runtime.h>

#define COL_DIM 4096
#define ROW_DIM 1024
#define NUM_LAYERS 3
#define KNN_E 16384
#define GENET_E 131072

typedef __attribute__((ext_vector_type(8))) _Float16 half8;
typedef __attribute__((ext_vector_type(2))) __fp16 fp16x2;
typedef __attribute__((ext_vector_type(4))) float f32x4;

__device__ inline unsigned short f2h(float f) {
  union { _Float16 h; unsigned short u; } c;
  c.h = (_Float16)f;
  return c.u;
}
__device__ inline unsigned int pkrtz(float a, float b) {
  union { fp16x2 p; unsigned int u; } c;
  c.p = __builtin_amdgcn_cvt_pkrtz(a, b);
  return c.u;
}
// 8 f32 -> half8 via packed RTZ converts
__device__ inline half8 cvt8h(float4 a, float4 b) {
  union { unsigned int u[4]; half8 v; } r;
  r.u[0] = pkrtz(a.x, a.y);
  r.u[1] = pkrtz(a.z, a.w);
  r.u[2] = pkrtz(b.x, b.y);
  r.u[3] = pkrtz(b.z, b.w);
  return r.v;
}

// ---------------- transpose + f16: in[R][C] -> outf/outh [C][R] ----------------
__global__ void transpose_split_kernel(const float* __restrict__ in,
                                       float* __restrict__ outf,
                                       unsigned short* __restrict__ outh,
                                       int R, int C) {
  __shared__ float tile[32][33];
  int c0 = blockIdx.x * 32, r0 = blockIdx.y * 32;
  int tx = threadIdx.x, ty = threadIdx.y; // 32 x 8
#pragma unroll
  for (int i = 0; i < 32; i += 8)
    tile[ty + i][tx] = in[(size_t)(r0 + ty + i) * C + c0 + tx];
  __syncthreads();
#pragma unroll
  for (int i = 0; i < 32; i += 8) {
    float v = tile[tx][ty + i];
    size_t o = (size_t)(c0 + ty + i) * R + r0 + tx;
    outf[o] = v;
    outh[o] = f2h(v);
  }
}

// ---------------- CSR build ----------------
__global__ void count_kernel(const int* __restrict__ dst, int E, int* __restrict__ cnt) {
  int e = blockIdx.x * 256 + threadIdx.x;
  if (e < E) atomicAdd(&cnt[dst[e]], 1);
}

__global__ void scan_kernel(const int* __restrict__ cnt, int* __restrict__ indptr, int n) {
  __shared__ int s[1024];
  __shared__ int base_s;
  int tid = threadIdx.x;
  if (tid == 0) { base_s = 0; indptr[0] = 0; }
  __syncthreads();
  for (int c = 0; c < n; c += 1024) {
    int i = c + tid;
    int v = (i < n) ? cnt[i] : 0;
    s[tid] = v;
    __syncthreads();
    for (int off = 1; off < 1024; off <<= 1) {
      int t = (tid >= off) ? s[tid - off] : 0;
      __syncthreads();
      s[tid] += t;
      __syncthreads();
    }
    if (i < n) indptr[i + 1] = base_s + s[tid];
    __syncthreads();
    if (tid == 0) base_s += s[1023];
    __syncthreads();
  }
}

__global__ void copy_int_kernel(const int* __restrict__ a, int* __restrict__ b, int n) {
  int i = blockIdx.x * 256 + threadIdx.x;
  if (i < n) b[i] = a[i];
}

__global__ void fill_kernel(const int* __restrict__ src, const int* __restrict__ dst, int E,
                            int* __restrict__ cursor, int* __restrict__ idx) {
  int e = blockIdx.x * 256 + threadIdx.x;
  if (e < E) {
    int p = atomicAdd(&cursor[dst[e]], 1);
    idx[p] = src[e];
  }
}

// ---------------- wave-per-bucket rank sort (deterministic: sorted by value) ---
__global__ void rank_sort_kernel(const int* __restrict__ indptr, int* __restrict__ idx,
                                 int n) {
  int wv = threadIdx.x >> 6, lane = threadIdx.x & 63;
  int b = blockIdx.x * (blockDim.x >> 6) + wv;
  if (b >= n) return;
  int lo = indptr[b];
  int d = indptr[b + 1] - lo;
  if (d <= 1) return;
  if (d <= 256) {
    int v0 = (lane < d) ? idx[lo + lane] : 0x7fffffff;
    int v1 = (64 + lane < d) ? idx[lo + 64 + lane] : 0x7fffffff;
    int v2 = (128 + lane < d) ? idx[lo + 128 + lane] : 0x7fffffff;
    int v3 = (192 + lane < d) ? idx[lo + 192 + lane] : 0x7fffffff;
    int r0 = 0, r1 = 0, r2 = 0, r3 = 0;
    for (int j = 0; j < d; j++) {
      int q = j >> 6;
      int sel = (q == 0) ? v0 : (q == 1) ? v1 : (q == 2) ? v2 : v3;
      int bj = __shfl(sel, j & 63);
      r0 += (bj < v0 || (bj == v0 && j < lane)) ? 1 : 0;
      r1 += (bj < v1 || (bj == v1 && j < 64 + lane)) ? 1 : 0;
      r2 += (bj < v2 || (bj == v2 && j < 128 + lane)) ? 1 : 0;
      r3 += (bj < v3 || (bj == v3 && j < 192 + lane)) ? 1 : 0;
    }
    if (lane < d) idx[lo + r0] = v0;
    if (64 + lane < d) idx[lo + r1] = v1;
    if (128 + lane < d) idx[lo + r2] = v2;
    if (192 + lane < d) idx[lo + r3] = v3;
  } else if (lane == 0) {
    for (int i = lo + 1; i < lo + d; i++) {
      int v = idx[i];
      int j = i - 1;
      while (j >= lo && idx[j] > v) { idx[j + 1] = idx[j]; j--; }
      idx[j + 1] = v;
    }
  }
}

// ---------------- neighbor mean, XCD-sliced, fp32 gather -> f16 out ------------
__global__ void agg_slice_kernel(const float* __restrict__ src,
                                 unsigned short* __restrict__ dh,
                                 const int* __restrict__ indptr,
                                 const int* __restrict__ idx, int D, int tprsh) {
  int tid = threadIdx.x;
  int d = blockIdx.y * (256 >> tprsh) + (tid >> tprsh);
  int k4 = blockIdx.x * (1 << tprsh) + (tid & ((1 << tprsh) - 1));
  int lo = indptr[d], hi = indptr[d + 1];
  float4 s = make_float4(0.f, 0.f, 0.f, 0.f);
  for (int j = lo; j < hi; j++) {
    float4 v = ((const float4*)(src + (size_t)idx[j] * D))[k4];
    s.x += v.x; s.y += v.y; s.z += v.z; s.w += v.w;
  }
  int c = hi - lo;
  float inv = 1.f / (float)(c > 0 ? c : 1);
  s.x *= inv; s.y *= inv; s.z *= inv; s.w *= inv;
  ushort4 h;
  h.x = f2h(s.x); h.y = f2h(s.y); h.z = f2h(s.z); h.w = f2h(s.w);
  ((ushort4*)(dh + (size_t)d * D))[k4] = h;
}

// ---------------- dual f16 MFMA NT GEMM (r8 ring, single sweep) ----------------
// P_kh[m][n] = sum_k Op(kh,A)[m,k] * Op(kh,B)[n,k]; kh = bid>>8 selects product.
// AF32=1: A-side fp32 weights staged raw, cvt_pkrtz'd in-reg; B-side f16 acts.
// AF32=0: roles swapped. 256 thr = 4 waves, 128x128 tile, wave tile 64x64.
// 48KB LDS (2 x 24KB: 16KB fp32 + 8KB f16), 2 blocks/CU.
// STAGE = exactly 6 GLDS -> counted vmcnt(6) (r8-proven accounting pattern).
// Swizzles (verified conflict-free): fp32 8-slot p^(r&7); f16 4-slot p^((r>>1)&3).
#define GBM 128
#define GBN 128
#define GBK 32

#define GLDS(g, l)                                                             \
  __builtin_amdgcn_global_load_lds(                                            \
      (const __attribute__((address_space(1))) void*)(g),                      \
      (__attribute__((address_space(3))) void*)(l), 16, 0, 0)

#define BAR()                                                                  \
  {                                                                            \
    asm volatile("" ::: "memory");                                             \
    __builtin_amdgcn_s_barrier();                                              \
    asm volatile("" ::: "memory");                                             \
  }

template <int AF32>
__global__ __launch_bounds__(256, 2) void dual_gemm_kernel(
    const float* __restrict__ Wf1, const float* __restrict__ Wf2,
    const unsigned short* __restrict__ Xh1, const unsigned short* __restrict__ Xh2,
    float* __restrict__ P0, float* __restrict__ P1, int Kloc) {
  // per buffer 24KB: [0,16K) fp32 [128][32]; [16K,24K) f16 [128][32].
  __shared__ char smraw[2][24576];
  const int tid = threadIdx.x;
  const int lane = tid & 63;
  const int wid = tid >> 6;
  const int wr = wid >> 1, wc = wid & 1;

  const int bid = blockIdx.x;
  const int kh = bid >> 8;
  const int tile = bid & 255;
  const int swz = (tile & 7) * 32 + (tile >> 3); // XCD-chunked
  const int bm0 = (swz >> 3) * GBM;
  const int bn0 = (swz & 7) * GBN;

  const float* Wf = kh ? Wf2 : Wf1;
  const unsigned short* Xh = kh ? Xh2 : Xh1;
  const size_t wrow = AF32 ? (size_t)bm0 : (size_t)bn0; // fp32-side tile rows
  const size_t xrow = AF32 ? (size_t)bn0 : (size_t)bm0; // f16-side tile rows

  // fp32 staging: 1024 16B-units, 4/thread (u = tid + 256v), row = 8 units,
  // physical slot q holds logical q^(r&7).
  const int u0 = tid, u1 = tid + 256, u2 = tid + 512, u3 = tid + 768;
  const int fr0 = u0 >> 3, fr1 = u1 >> 3, fr2 = u2 >> 3, fr3 = u3 >> 3;
  const int fc0 = ((u0 & 7) ^ (fr0 & 7)) * 4;
  const int fc1 = ((u1 & 7) ^ (fr1 & 7)) * 4;
  const int fc2 = ((u2 & 7) ^ (fr2 & 7)) * 4;
  const int fc3 = ((u3 & 7) ^ (fr3 & 7)) * 4;
  const float* gF0 = Wf + (wrow + fr0) * Kloc + fc0;
  const float* gF1 = Wf + (wrow + fr1) * Kloc + fc1;
  const float* gF2 = Wf + (wrow + fr2) * Kloc + fc2;
  const float* gF3 = Wf + (wrow + fr3) * Kloc + fc3;
  // f16 staging: 512 16B-units, 2/thread, row = 4 units, slot q^((r>>1)&3).
  const int hr0 = u0 >> 2, hr1 = u1 >> 2;
  const int hc0 = ((u0 & 3) ^ ((hr0 >> 1) & 3)) * 8;
  const int hc1 = ((u1 & 3) ^ ((hr1 >> 1) & 3)) * 8;
  const unsigned short* gH0 = Xh + (xrow + hr0) * Kloc + hc0;
  const unsigned short* gH1 = Xh + (xrow + hr1) * Kloc + hc1;

  // exactly 6 GLDS per STAGE (vmcnt counting relies on it)
#define STAGE(buf)                                                             \
  {                                                                            \
    char* base = &smraw[buf][0];                                               \
    GLDS(gF0, base + u0 * 16); GLDS(gF1, base + u1 * 16);                      \
    GLDS(gF2, base + u2 * 16); GLDS(gF3, base + u3 * 16);                      \
    GLDS(gH0, base + 16384 + u0 * 16); GLDS(gH1, base + 16384 + u1 * 16);      \
    gF0 += GBK; gF1 += GBK; gF2 += GBK; gF3 += GBK;                            \
    gH0 += GBK; gH1 += GBK;                                                    \
  }

  // fragment ds_read offsets
  int offH[4];         // f16 side, ushort units
  int offF[4][2];      // fp32 side, float units (2 x float4 per frag)
  {
    int s = lane >> 4;
#pragma unroll
    for (int i = 0; i < 4; i++) {
      int rh = (AF32 ? wc : wr) * 64 + i * 16 + (lane & 15);
      offH[i] = rh * 32 + ((s ^ ((rh >> 1) & 3)) * 8);
      int rf = (AF32 ? wr : wc) * 64 + i * 16 + (lane & 15);
      offF[i][0] = rf * 32 + (((2 * s) ^ (rf & 7)) * 4);
      offF[i][1] = rf * 32 + (((2 * s + 1) ^ (rf & 7)) * 4);
    }
  }

  f32x4 acc[4][4];
#pragma unroll
  for (int i = 0; i < 4; i++)
#pragma unroll
    for (int j = 0; j < 4; j++) acc[i][j] = (f32x4)(0.f);

  const int nt = Kloc / GBK;
  STAGE(0);
  STAGE(1);
  int cur = 0;
  for (int t = 0; t < nt; t++) {
    if (t < nt - 1) {
      asm volatile("s_waitcnt vmcnt(6)" ::: "memory"); // tile t landed
    } else {
      asm volatile("s_waitcnt vmcnt(0)" ::: "memory");
    }
    BAR();
    const float* smF = (const float*)&smraw[cur][0];
    const unsigned short* smH = (const unsigned short*)&smraw[cur][16384];
    half8 cw[4], rd[4];
#pragma unroll
    for (int i = 0; i < 4; i++) {
      float4 a = *(const float4*)&smF[offF[i][0]];
      float4 b = *(const float4*)&smF[offF[i][1]];
      cw[i] = cvt8h(a, b);
      rd[i] = *(const half8*)&smH[offH[i]];
    }
    __builtin_amdgcn_s_setprio(1);
    if constexpr (AF32) {
#pragma unroll
      for (int i = 0; i < 4; i++)
#pragma unroll
        for (int j = 0; j < 4; j++)
          acc[i][j] = __builtin_amdgcn_mfma_f32_16x16x32_f16(cw[i], rd[j],
                                                             acc[i][j], 0, 0, 0);
    } else {
#pragma unroll
      for (int i = 0; i < 4; i++)
#pragma unroll
        for (int j = 0; j < 4; j++)
          acc[i][j] = __builtin_amdgcn_mfma_f32_16x16x32_f16(rd[i], cw[j],
                                                             acc[i][j], 0, 0, 0);
    }
    __builtin_amdgcn_s_setprio(0);
    BAR(); // all waves done reading sm[cur]
    if (t + 2 < nt) STAGE(cur);
    cur ^= 1;
  }

  float* P = kh ? P1 : P0;
  const int rowq = (lane >> 4) * 4;
  const int colq = lane & 15;
#pragma unroll
  for (int i = 0; i < 4; i++) {
#pragma unroll
    for (int j = 0; j < 4; j++) {
#pragma unroll
      for (int e = 0; e < 4; e++) {
        int row = bm0 + wr * 64 + i * 16 + rowq + e;
        int col = bn0 + wc * 64 + j * 16 + colq;
        P[(size_t)row * 1024 + col] = acc[i][j][e];
      }
    }
  }
}

// ---------------- combine: C = leaky(P0+P1 + bias[row]) + f16 copy -------------
__global__ void combine_split_kernel(const float* __restrict__ P0, const float* __restrict__ P1,
                                     const float* __restrict__ bias, float* __restrict__ Cf,
                                     unsigned short* __restrict__ Ch) {
  int i = blockIdx.x * 256 + threadIdx.x; // float4 index, 1M total
  float4 a = ((const float4*)P0)[i];
  float4 b = ((const float4*)P1)[i];
  float bb = bias[(i * 4) >> 10];
  float4 v;
  v.x = a.x + b.x + bb;
  v.y = a.y + b.y + bb;
  v.z = a.z + b.z + bb;
  v.w = a.w + b.w + bb;
  v.x = v.x > 0.f ? v.x : 0.01f * v.x;
  v.y = v.y > 0.f ? v.y : 0.01f * v.y;
  v.z = v.z > 0.f ? v.z : 0.01f * v.z;
  v.w = v.w > 0.f ? v.w : 0.01f * v.w;
  ((float4*)Cf)[i] = v;
  ushort4 h;
  h.x = f2h(v.x); h.y = f2h(v.y); h.z = f2h(v.z); h.w = f2h(v.w);
  ((ushort4*)Ch)[i] = h;
}

// ---------------- combine: C = leaky(P0+P1 + bias[col]) ----------------
__global__ void combine_kernel(const float* __restrict__ P0, const float* __restrict__ P1,
                               const float* __restrict__ bias, float* __restrict__ C) {
  int i = blockIdx.x * 256 + threadIdx.x;
  float4 a = ((const float4*)P0)[i];
  float4 b = ((const float4*)P1)[i];
  float4 bb = *(const float4*)(bias + ((i * 4) & 1023));
  float4 v;
  v.x = a.x + b.x + bb.x;
  v.y = a.y + b.y + bb.y;
  v.z = a.z + b.z + bb.z;
  v.w = a.w + b.w + bb.w;
  v.x = v.x > 0.f ? v.x : 0.01f * v.x;
  v.y = v.y > 0.f ? v.y : 0.01f * v.y;
  v.z = v.z > 0.f ? v.z : 0.01f * v.z;
  v.w = v.w > 0.f ? v.w : 0.01f * v.w;
  ((float4*)C)[i] = v;
}

extern "C" void kernel_launch(void* const* d_in, const int* in_sizes, int n_in,
                              void* d_out, int out_size, void* d_ws, size_t ws_size,
                              hipStream_t stream) {
  const float* x      = (const float*)d_in[0];
  const float* col_Wl = (const float*)d_in[1];
  const float* col_Wr = (const float*)d_in[2];
  const float* col_b  = (const float*)d_in[3];
  const float* row_Wl = (const float*)d_in[4];
  const float* row_Wr = (const float*)d_in[5];
  const float* row_b  = (const float*)d_in[6];
  const int*   knn    = (const int*)d_in[7];   // [2][KNN_E]
  const int*   genet  = (const int*)d_in[8];   // [2][GENET_E]
  float* out = (float*)d_out;

  const size_t MAT = (size_t)COL_DIM * ROW_DIM; // 4M elements
  char* w = (char*)d_ws;
  float* ET  = (float*)w; w += MAT * 4;                   // [1024][4096]
  float* E1  = (float*)w; w += MAT * 4;                   // [4096][1024]
  unsigned short* ETh = (unsigned short*)w; w += MAT * 2; // f16
  unsigned short* Mh  = (unsigned short*)w; w += MAT * 2; // knn mean f16
  unsigned short* Gh  = (unsigned short*)w; w += MAT * 2; // genet mean f16
  unsigned short* E1h = (unsigned short*)w; w += MAT * 2; // f16
  float* PP0 = (float*)w; w += MAT * 4;
  float* PP1 = (float*)w; w += MAT * 4;
  int* kcnt = (int*)w; w += 1024 * 4;
  int* kptr = (int*)w; w += 1025 * 4;
  int* kidx = (int*)w; w += KNN_E * 4;
  int* gcnt = (int*)w; w += 4096 * 4;
  int* gptr = (int*)w; w += 4097 * 4;
  int* gidx = (int*)w; w += (size_t)GENET_E * 4;

  // ---- CSR build (deterministic via per-bucket value sort) ----
  hipMemsetAsync(kcnt, 0, 1024 * 4, stream);
  hipMemsetAsync(gcnt, 0, 4096 * 4, stream);
  count_kernel<<<KNN_E / 256, 256, 0, stream>>>(knn + KNN_E, KNN_E, kcnt);
  count_kernel<<<GENET_E / 256, 256, 0, stream>>>(genet + GENET_E, GENET_E, gcnt);
  scan_kernel<<<1, 1024, 0, stream>>>(kcnt, kptr, 1024);
  scan_kernel<<<1, 1024, 0, stream>>>(gcnt, gptr, 4096);
  copy_int_kernel<<<4, 256, 0, stream>>>(kptr, kcnt, 1024);
  copy_int_kernel<<<16, 256, 0, stream>>>(gptr, gcnt, 4096);
  fill_kernel<<<KNN_E / 256, 256, 0, stream>>>(knn, knn + KNN_E, KNN_E, kcnt, kidx);
  fill_kernel<<<GENET_E / 256, 256, 0, stream>>>(genet, genet + GENET_E, GENET_E, gcnt, gidx);
  rank_sort_kernel<<<256, 256, 0, stream>>>(kptr, kidx, 1024);
  rank_sort_kernel<<<1024, 256, 0, stream>>>(gptr, gidx, 4096);

  const float* Ein = x;
  for (int i = 0; i < NUM_LAYERS; i++) {
    const float* cWl = col_Wl + (size_t)i * COL_DIM * COL_DIM;
    const float* cWr = col_Wr + (size_t)i * COL_DIM * COL_DIM;
    const float* cb  = col_b + (size_t)i * COL_DIM;
    const float* rWl = row_Wl + (size_t)i * ROW_DIM * ROW_DIM;
    const float* rWr = row_Wr + (size_t)i * ROW_DIM * ROW_DIM;
    const float* rb  = row_b + (size_t)i * ROW_DIM;

    // ---- column branch: E1 = leaky(cWl@M^T + cWr@ET^T + cb[row]) ----
    transpose_split_kernel<<<dim3(ROW_DIM / 32, COL_DIM / 32), dim3(32, 8), 0, stream>>>(
        Ein, ET, ETh, COL_DIM, ROW_DIM);
    agg_slice_kernel<<<dim3(8, 512), 256, 0, stream>>>(ET, Mh, kptr, kidx,
                                                       COL_DIM, 7);
    dual_gemm_kernel<1><<<512, 256, 0, stream>>>(
        cWl, cWr, Mh, ETh, PP0, PP1, COL_DIM);
    combine_split_kernel<<<4096, 256, 0, stream>>>(PP0, PP1, cb, E1, E1h);

    // ---- row branch: out = leaky(G@rWl^T + E1@rWr^T + rb[col]) ----
    agg_slice_kernel<<<dim3(8, 512), 256, 0, stream>>>(E1, Gh, gptr, gidx,
                                                       ROW_DIM, 5);
    dual_gemm_kernel<0><<<512, 256, 0, stream>>>(
        rWl, rWr, Gh, E1h, PP0, PP1, ROW_DIM);
    combine_kernel<<<4096, 256, 0, stream>>>(PP0, PP1, rb, out);

    Ein = out;
  }
}

// Round 19
// 803.992 us; speedup vs baseline: 1.4889x; 1.1029x over previous
//
#include <hip/hip_runtime.h>

#define COL_DIM 4096
#define ROW_DIM 1024
#define NUM_LAYERS 3
#define KNN_E 16384
#define GENET_E 131072

typedef __attribute__((ext_vector_type(8))) _Float16 half8;
typedef __attribute__((ext_vector_type(4))) float f32x4;

__device__ inline unsigned short f2h(float f) {
  union { _Float16 h; unsigned short u; } c;
  c.h = (_Float16)f;
  return c.u;
}

// ---------------- transpose + f16: in[R][C] -> outf/outh [C][R] ----------------
__global__ void transpose_split_kernel(const float* __restrict__ in,
                                       float* __restrict__ outf,
                                       unsigned short* __restrict__ outh,
                                       int R, int C) {
  __shared__ float tile[32][33];
  int c0 = blockIdx.x * 32, r0 = blockIdx.y * 32;
  int tx = threadIdx.x, ty = threadIdx.y; // 32 x 8
#pragma unroll
  for (int i = 0; i < 32; i += 8)
    tile[ty + i][tx] = in[(size_t)(r0 + ty + i) * C + c0 + tx];
  __syncthreads();
#pragma unroll
  for (int i = 0; i < 32; i += 8) {
    float v = tile[tx][ty + i];
    size_t o = (size_t)(c0 + ty + i) * R + r0 + tx;
    outf[o] = v;
    outh[o] = f2h(v);
  }
}

// ---------------- fp32 -> f16 plane (weights) ----------------
__global__ void split_f16_kernel(const float* __restrict__ src,
                                 unsigned short* __restrict__ dh, int n4) {
  int i = blockIdx.x * 256 + threadIdx.x;
  int stride = gridDim.x * 256;
  for (; i < n4; i += stride) {
    float4 v = ((const float4*)src)[i];
    ushort4 h;
    h.x = f2h(v.x); h.y = f2h(v.y); h.z = f2h(v.z); h.w = f2h(v.w);
    ((ushort4*)dh)[i] = h;
  }
}

// ---------------- CSR build ----------------
__global__ void count_kernel(const int* __restrict__ dst, int E, int* __restrict__ cnt) {
  int e = blockIdx.x * 256 + threadIdx.x;
  if (e < E) atomicAdd(&cnt[dst[e]], 1);
}

__global__ void scan_kernel(const int* __restrict__ cnt, int* __restrict__ indptr, int n) {
  __shared__ int s[1024];
  __shared__ int base_s;
  int tid = threadIdx.x;
  if (tid == 0) { base_s = 0; indptr[0] = 0; }
  __syncthreads();
  for (int c = 0; c < n; c += 1024) {
    int i = c + tid;
    int v = (i < n) ? cnt[i] : 0;
    s[tid] = v;
    __syncthreads();
    for (int off = 1; off < 1024; off <<= 1) {
      int t = (tid >= off) ? s[tid - off] : 0;
      __syncthreads();
      s[tid] += t;
      __syncthreads();
    }
    if (i < n) indptr[i + 1] = base_s + s[tid];
    __syncthreads();
    if (tid == 0) base_s += s[1023];
    __syncthreads();
  }
}

__global__ void copy_int_kernel(const int* __restrict__ a, int* __restrict__ b, int n) {
  int i = blockIdx.x * 256 + threadIdx.x;
  if (i < n) b[i] = a[i];
}

__global__ void fill_kernel(const int* __restrict__ src, const int* __restrict__ dst, int E,
                            int* __restrict__ cursor, int* __restrict__ idx) {
  int e = blockIdx.x * 256 + threadIdx.x;
  if (e < E) {
    int p = atomicAdd(&cursor[dst[e]], 1);
    idx[p] = src[e];
  }
}

// ---------------- wave-per-bucket rank sort (deterministic: sorted by value) ---
__global__ void rank_sort_kernel(const int* __restrict__ indptr, int* __restrict__ idx,
                                 int n) {
  int wv = threadIdx.x >> 6, lane = threadIdx.x & 63;
  int b = blockIdx.x * (blockDim.x >> 6) + wv;
  if (b >= n) return;
  int lo = indptr[b];
  int d = indptr[b + 1] - lo;
  if (d <= 1) return;
  if (d <= 256) {
    int v0 = (lane < d) ? idx[lo + lane] : 0x7fffffff;
    int v1 = (64 + lane < d) ? idx[lo + 64 + lane] : 0x7fffffff;
    int v2 = (128 + lane < d) ? idx[lo + 128 + lane] : 0x7fffffff;
    int v3 = (192 + lane < d) ? idx[lo + 192 + lane] : 0x7fffffff;
    int r0 = 0, r1 = 0, r2 = 0, r3 = 0;
    for (int j = 0; j < d; j++) {
      int q = j >> 6;
      int sel = (q == 0) ? v0 : (q == 1) ? v1 : (q == 2) ? v2 : v3;
      int bj = __shfl(sel, j & 63);
      r0 += (bj < v0 || (bj == v0 && j < lane)) ? 1 : 0;
      r1 += (bj < v1 || (bj == v1 && j < 64 + lane)) ? 1 : 0;
      r2 += (bj < v2 || (bj == v2 && j < 128 + lane)) ? 1 : 0;
      r3 += (bj < v3 || (bj == v3 && j < 192 + lane)) ? 1 : 0;
    }
    if (lane < d) idx[lo + r0] = v0;
    if (64 + lane < d) idx[lo + r1] = v1;
    if (128 + lane < d) idx[lo + r2] = v2;
    if (192 + lane < d) idx[lo + r3] = v3;
  } else if (lane == 0) {
    for (int i = lo + 1; i < lo + d; i++) {
      int v = idx[i];
      int j = i - 1;
      while (j >= lo && idx[j] > v) { idx[j + 1] = idx[j]; j--; }
      idx[j + 1] = v;
    }
  }
}

// ---------------- neighbor mean, XCD-sliced, fp32 gather -> f16 out ------------
__global__ void agg_slice_kernel(const float* __restrict__ src,
                                 unsigned short* __restrict__ dh,
                                 const int* __restrict__ indptr,
                                 const int* __restrict__ idx, int D, int tprsh) {
  int tid = threadIdx.x;
  int d = blockIdx.y * (256 >> tprsh) + (tid >> tprsh);
  int k4 = blockIdx.x * (1 << tprsh) + (tid & ((1 << tprsh) - 1));
  int lo = indptr[d], hi = indptr[d + 1];
  float4 s = make_float4(0.f, 0.f, 0.f, 0.f);
  for (int j = lo; j < hi; j++) {
    float4 v = ((const float4*)(src + (size_t)idx[j] * D))[k4];
    s.x += v.x; s.y += v.y; s.z += v.z; s.w += v.w;
  }
  int c = hi - lo;
  float inv = 1.f / (float)(c > 0 ? c : 1);
  s.x *= inv; s.y *= inv; s.z *= inv; s.w *= inv;
  ushort4 h;
  h.x = f2h(s.x); h.y = f2h(s.y); h.z = f2h(s.z); h.w = f2h(s.w);
  ((ushort4*)(dh + (size_t)d * D))[k4] = h;
}

// ---------------- dual f16 MFMA NT GEMM (pure f16, splitK=2, 4 blocks/CU) ------
// Grid 1024: q = swz>>8: product p=q>>1, K-half kh=q&1; P[q] = raw partial.
// A = m-side (4096 rows), B = n-side (1024 rows), both f16 planes.
// 256 thr = 4 waves, 128x128 tile, wave tile 64x64; BK=32.
// LDS 2 buf x {A,B} x 8KB = 32KB -> 4 blocks/CU (the TLP that hides barriers).
// STAGE = exactly 4 GLDS -> counted vmcnt(4).
// Swizzle (verified): 4 slots/row of 16B; physical p holds logical p^((r>>1)&3).
#define GBM 128
#define GBN 128
#define GBK 32

#define GLDS(g, l)                                                             \
  __builtin_amdgcn_global_load_lds(                                            \
      (const __attribute__((address_space(1))) void*)(g),                      \
      (__attribute__((address_space(3))) void*)(l), 16, 0, 0)

#define BAR()                                                                  \
  {                                                                            \
    asm volatile("" ::: "memory");                                             \
    __builtin_amdgcn_s_barrier();                                              \
    asm volatile("" ::: "memory");                                             \
  }

__global__ __launch_bounds__(256, 4) void dual_gemm_kernel(
    const unsigned short* __restrict__ A1, const unsigned short* __restrict__ A2,
    const unsigned short* __restrict__ B1, const unsigned short* __restrict__ B2,
    float* __restrict__ P0, float* __restrict__ P1,
    float* __restrict__ P2, float* __restrict__ P3, int Ktot, int Kblk) {
  __shared__ unsigned short sm[2][2][4096]; // buf x {A,B} x [128][32] f16 = 32KB
  const int tid = threadIdx.x;
  const int lane = tid & 63;
  const int wid = tid >> 6;
  const int wr = wid >> 1, wc = wid & 1;

  const int bid = blockIdx.x;                   // 1024 blocks
  const int swz = (bid & 7) * 128 + (bid >> 3); // XCD-chunked
  const int q = swz >> 8;                       // 0..3
  const int p = q >> 1, kh = q & 1;
  const int tile = swz & 255;                   // 32 m x 8 n
  const int bm0 = (tile >> 3) * GBM;
  const int bn0 = (tile & 7) * GBN;
  const size_t kbase = (size_t)kh * Kblk;

  const unsigned short* A = p ? A2 : A1;
  const unsigned short* B = p ? B2 : B1;

  // staging: per operand 512 units of 16B; thread handles u0=tid, u1=tid+256.
  // physical slot p2 = u&3 sources logical p2 ^ ((r>>1)&3).
  const int u0 = tid, u1 = tid + 256;
  const int r0 = u0 >> 2, r1 = u1 >> 2;
  const int c0 = ((u0 & 3) ^ ((r0 >> 1) & 3)) * 8;
  const int c1 = ((u1 & 3) ^ ((r1 >> 1) & 3)) * 8;
  const unsigned short* gA0 = A + (size_t)(bm0 + r0) * Ktot + kbase + c0;
  const unsigned short* gA1 = A + (size_t)(bm0 + r1) * Ktot + kbase + c1;
  const unsigned short* gB0 = B + (size_t)(bn0 + r0) * Ktot + kbase + c0;
  const unsigned short* gB1 = B + (size_t)(bn0 + r1) * Ktot + kbase + c1;

  // exactly 4 GLDS per STAGE (vmcnt counting relies on it)
#define STAGE(buf)                                                             \
  {                                                                            \
    GLDS(gA0, &sm[buf][0][u0 * 8]); GLDS(gA1, &sm[buf][0][u1 * 8]);            \
    GLDS(gB0, &sm[buf][1][u0 * 8]); GLDS(gB1, &sm[buf][1][u1 * 8]);            \
    gA0 += GBK; gA1 += GBK; gB0 += GBK; gB1 += GBK;                            \
  }

  // fragment ds_read offsets (ushort units)
  int offA[4], offB[4];
  {
    int s = lane >> 4;
#pragma unroll
    for (int i = 0; i < 4; i++) {
      int rA = wr * 64 + i * 16 + (lane & 15);
      offA[i] = rA * 32 + ((s ^ ((rA >> 1) & 3)) * 8);
      int rB = wc * 64 + i * 16 + (lane & 15);
      offB[i] = rB * 32 + ((s ^ ((rB >> 1) & 3)) * 8);
    }
  }

  f32x4 acc[4][4];
#pragma unroll
  for (int i = 0; i < 4; i++)
#pragma unroll
    for (int j = 0; j < 4; j++) acc[i][j] = (f32x4)(0.f);

  const int nt = Kblk / GBK; // col: 64, row: 16
  STAGE(0);
  STAGE(1);
  int cur = 0;
  for (int t = 0; t < nt; t++) {
    if (t < nt - 1) {
      asm volatile("s_waitcnt vmcnt(4)" ::: "memory"); // tile t landed
    } else {
      asm volatile("s_waitcnt vmcnt(0)" ::: "memory");
    }
    BAR();
    const unsigned short* smA = &sm[cur][0][0];
    const unsigned short* smB = &sm[cur][1][0];
    half8 av[4], bv[4];
#pragma unroll
    for (int i = 0; i < 4; i++) {
      av[i] = *(const half8*)&smA[offA[i]];
      bv[i] = *(const half8*)&smB[offB[i]];
    }
    __builtin_amdgcn_s_setprio(1);
#pragma unroll
    for (int i = 0; i < 4; i++)
#pragma unroll
      for (int j = 0; j < 4; j++)
        acc[i][j] = __builtin_amdgcn_mfma_f32_16x16x32_f16(av[i], bv[j],
                                                           acc[i][j], 0, 0, 0);
    __builtin_amdgcn_s_setprio(0);
    BAR(); // all waves done reading sm[cur]
    if (t + 2 < nt) STAGE(cur);
    cur ^= 1;
  }

  float* P = q == 0 ? P0 : q == 1 ? P1 : q == 2 ? P2 : P3;
  const int rowq = (lane >> 4) * 4;
  const int colq = lane & 15;
#pragma unroll
  for (int i = 0; i < 4; i++) {
#pragma unroll
    for (int j = 0; j < 4; j++) {
#pragma unroll
      for (int e = 0; e < 4; e++) {
        int row = bm0 + wr * 64 + i * 16 + rowq + e;
        int col = bn0 + wc * 64 + j * 16 + colq;
        P[(size_t)row * 1024 + col] = acc[i][j][e];
      }
    }
  }
}

// ---------------- combine4: C = leaky(P0..P3 + bias[row]) + f16 copy -----------
__global__ void combine_split_kernel(const float* __restrict__ P0, const float* __restrict__ P1,
                                     const float* __restrict__ P2, const float* __restrict__ P3,
                                     const float* __restrict__ bias, float* __restrict__ Cf,
                                     unsigned short* __restrict__ Ch) {
  int i = blockIdx.x * 256 + threadIdx.x; // float4 index, 1M total
  float4 a = ((const float4*)P0)[i];
  float4 b = ((const float4*)P1)[i];
  float4 c = ((const float4*)P2)[i];
  float4 d = ((const float4*)P3)[i];
  float bb = bias[(i * 4) >> 10];
  float4 v;
  v.x = a.x + b.x + c.x + d.x + bb;
  v.y = a.y + b.y + c.y + d.y + bb;
  v.z = a.z + b.z + c.z + d.z + bb;
  v.w = a.w + b.w + c.w + d.w + bb;
  v.x = v.x > 0.f ? v.x : 0.01f * v.x;
  v.y = v.y > 0.f ? v.y : 0.01f * v.y;
  v.z = v.z > 0.f ? v.z : 0.01f * v.z;
  v.w = v.w > 0.f ? v.w : 0.01f * v.w;
  ((float4*)Cf)[i] = v;
  ushort4 h;
  h.x = f2h(v.x); h.y = f2h(v.y); h.z = f2h(v.z); h.w = f2h(v.w);
  ((ushort4*)Ch)[i] = h;
}

// ---------------- combine4: C = leaky(P0..P3 + bias[col]) ----------------
__global__ void combine_kernel(const float* __restrict__ P0, const float* __restrict__ P1,
                               const float* __restrict__ P2, const float* __restrict__ P3,
                               const float* __restrict__ bias, float* __restrict__ C) {
  int i = blockIdx.x * 256 + threadIdx.x;
  float4 a = ((const float4*)P0)[i];
  float4 b = ((const float4*)P1)[i];
  float4 c = ((const float4*)P2)[i];
  float4 d = ((const float4*)P3)[i];
  float4 bb = *(const float4*)(bias + ((i * 4) & 1023));
  float4 v;
  v.x = a.x + b.x + c.x + d.x + bb.x;
  v.y = a.y + b.y + c.y + d.y + bb.y;
  v.z = a.z + b.z + c.z + d.z + bb.z;
  v.w = a.w + b.w + c.w + d.w + bb.w;
  v.x = v.x > 0.f ? v.x : 0.01f * v.x;
  v.y = v.y > 0.f ? v.y : 0.01f * v.y;
  v.z = v.z > 0.f ? v.z : 0.01f * v.z;
  v.w = v.w > 0.f ? v.w : 0.01f * v.w;
  ((float4*)C)[i] = v;
}

extern "C" void kernel_launch(void* const* d_in, const int* in_sizes, int n_in,
                              void* d_out, int out_size, void* d_ws, size_t ws_size,
                              hipStream_t stream) {
  const float* x      = (const float*)d_in[0];
  const float* col_Wl = (const float*)d_in[1];
  const float* col_Wr = (const float*)d_in[2];
  const float* col_b  = (const float*)d_in[3];
  const float* row_Wl = (const float*)d_in[4];
  const float* row_Wr = (const float*)d_in[5];
  const float* row_b  = (const float*)d_in[6];
  const int*   knn    = (const int*)d_in[7];   // [2][KNN_E]
  const int*   genet  = (const int*)d_in[8];   // [2][GENET_E]
  float* out = (float*)d_out;

  const size_t MAT = (size_t)COL_DIM * ROW_DIM; // 4M elements
  const size_t WCOL = (size_t)COL_DIM * COL_DIM;
  const size_t WROW = (size_t)ROW_DIM * ROW_DIM;
  char* w = (char*)d_ws;
  float* ET  = (float*)w; w += MAT * 4;                   // [1024][4096]
  float* E1  = (float*)w; w += MAT * 4;                   // [4096][1024]
  unsigned short* ETh = (unsigned short*)w; w += MAT * 2; // f16
  unsigned short* Mh  = (unsigned short*)w; w += MAT * 2; // knn mean f16
  unsigned short* Gh  = (unsigned short*)w; w += MAT * 2; // genet mean f16
  unsigned short* E1h = (unsigned short*)w; w += MAT * 2; // f16
  unsigned short* WH1 = (unsigned short*)w; w += WCOL * 2; // col Wl f16 (32MB)
  unsigned short* WH2 = (unsigned short*)w; w += WCOL * 2; // col Wr f16 (32MB)
  unsigned short* RH1 = (unsigned short*)w; w += WROW * 2; // row Wl f16 (2MB)
  unsigned short* RH2 = (unsigned short*)w; w += WROW * 2; // row Wr f16 (2MB)
  float* PP0 = (float*)w; w += MAT * 4;
  float* PP1 = (float*)w; w += MAT * 4;
  float* PP2 = (float*)w; w += MAT * 4;
  float* PP3 = (float*)w; w += MAT * 4;
  int* kcnt = (int*)w; w += 1024 * 4;
  int* kptr = (int*)w; w += 1025 * 4;
  int* kidx = (int*)w; w += KNN_E * 4;
  int* gcnt = (int*)w; w += 4096 * 4;
  int* gptr = (int*)w; w += 4097 * 4;
  int* gidx = (int*)w; w += (size_t)GENET_E * 4;

  // ---- CSR build (deterministic via per-bucket value sort) ----
  hipMemsetAsync(kcnt, 0, 1024 * 4, stream);
  hipMemsetAsync(gcnt, 0, 4096 * 4, stream);
  count_kernel<<<KNN_E / 256, 256, 0, stream>>>(knn + KNN_E, KNN_E, kcnt);
  count_kernel<<<GENET_E / 256, 256, 0, stream>>>(genet + GENET_E, GENET_E, gcnt);
  scan_kernel<<<1, 1024, 0, stream>>>(kcnt, kptr, 1024);
  scan_kernel<<<1, 1024, 0, stream>>>(gcnt, gptr, 4096);
  copy_int_kernel<<<4, 256, 0, stream>>>(kptr, kcnt, 1024);
  copy_int_kernel<<<16, 256, 0, stream>>>(gptr, gcnt, 4096);
  fill_kernel<<<KNN_E / 256, 256, 0, stream>>>(knn, knn + KNN_E, KNN_E, kcnt, kidx);
  fill_kernel<<<GENET_E / 256, 256, 0, stream>>>(genet, genet + GENET_E, GENET_E, gcnt, gidx);
  rank_sort_kernel<<<256, 256, 0, stream>>>(kptr, kidx, 1024);
  rank_sort_kernel<<<1024, 256, 0, stream>>>(gptr, gidx, 4096);

  const float* Ein = x;
  for (int i = 0; i < NUM_LAYERS; i++) {
    const float* cWl = col_Wl + (size_t)i * WCOL;
    const float* cWr = col_Wr + (size_t)i * WCOL;
    const float* cb  = col_b + (size_t)i * COL_DIM;
    const float* rWl = row_Wl + (size_t)i * WROW;
    const float* rWr = row_Wr + (size_t)i * WROW;
    const float* rb  = row_b + (size_t)i * ROW_DIM;

    // ---- column branch: E1 = leaky(cWl@M^T + cWr@ET^T + cb[row]) ----
    transpose_split_kernel<<<dim3(ROW_DIM / 32, COL_DIM / 32), dim3(32, 8), 0, stream>>>(
        Ein, ET, ETh, COL_DIM, ROW_DIM);
    agg_slice_kernel<<<dim3(8, 512), 256, 0, stream>>>(ET, Mh, kptr, kidx,
                                                       COL_DIM, 7);
    split_f16_kernel<<<2048, 256, 0, stream>>>(cWl, WH1, (int)(WCOL / 4));
    split_f16_kernel<<<2048, 256, 0, stream>>>(cWr, WH2, (int)(WCOL / 4));
    dual_gemm_kernel<<<1024, 256, 0, stream>>>(
        WH1, WH2, Mh, ETh, PP0, PP1, PP2, PP3, COL_DIM, COL_DIM / 2);
    combine_split_kernel<<<4096, 256, 0, stream>>>(PP0, PP1, PP2, PP3, cb, E1, E1h);

    // ---- row branch: out = leaky(G@rWl^T + E1@rWr^T + rb[col]) ----
    agg_slice_kernel<<<dim3(8, 512), 256, 0, stream>>>(E1, Gh, gptr, gidx,
                                                       ROW_DIM, 5);
    split_f16_kernel<<<1024, 256, 0, stream>>>(rWl, RH1, (int)(WROW / 4));
    split_f16_kernel<<<1024, 256, 0, stream>>>(rWr, RH2, (int)(WROW / 4));
    dual_gemm_kernel<<<1024, 256, 0, stream>>>(
        Gh, E1h, RH1, RH2, PP0, PP1, PP2, PP3, ROW_DIM, ROW_DIM / 2);
    combine_kernel<<<4096, 256, 0, stream>>>(PP0, PP1, PP2, PP3, rb, out);

    Ein = out;
  }
}

// Round 20
// 732.911 us; speedup vs baseline: 1.6333x; 1.0970x over previous
//
#include <hip/hip_runtime.h>

#define COL_DIM 4096
#define ROW_DIM 1024
#define NUM_LAYERS 3
#define KNN_E 16384
#define GENET_E 131072

typedef __attribute__((ext_vector_type(8))) _Float16 half8;
typedef __attribute__((ext_vector_type(4))) float f32x4;

__device__ inline unsigned short f2h(float f) {
  union { _Float16 h; unsigned short u; } c;
  c.h = (_Float16)f;
  return c.u;
}

// ---------------- transpose -> f16: in[R][C] fp32 -> outh[C][R] f16 ------------
__global__ void transpose_h_kernel(const float* __restrict__ in,
                                   unsigned short* __restrict__ outh,
                                   int R, int C) {
  __shared__ float tile[32][33];
  int c0 = blockIdx.x * 32, r0 = blockIdx.y * 32;
  int tx = threadIdx.x, ty = threadIdx.y; // 32 x 8
#pragma unroll
  for (int i = 0; i < 32; i += 8)
    tile[ty + i][tx] = in[(size_t)(r0 + ty + i) * C + c0 + tx];
  __syncthreads();
#pragma unroll
  for (int i = 0; i < 32; i += 8) {
    float v = tile[tx][ty + i];
    outh[(size_t)(c0 + ty + i) * R + r0 + tx] = f2h(v);
  }
}

// ---------------- fp32 -> f16 plane (weights) ----------------
__global__ void split_f16_kernel(const float* __restrict__ src,
                                 unsigned short* __restrict__ dh, int n4) {
  int i = blockIdx.x * 256 + threadIdx.x;
  int stride = gridDim.x * 256;
  for (; i < n4; i += stride) {
    float4 v = ((const float4*)src)[i];
    ushort4 h;
    h.x = f2h(v.x); h.y = f2h(v.y); h.z = f2h(v.z); h.w = f2h(v.w);
    ((ushort4*)dh)[i] = h;
  }
}

// ---------------- CSR build ----------------
__global__ void count_kernel(const int* __restrict__ dst, int E, int* __restrict__ cnt) {
  int e = blockIdx.x * 256 + threadIdx.x;
  if (e < E) atomicAdd(&cnt[dst[e]], 1);
}

__global__ void scan_kernel(const int* __restrict__ cnt, int* __restrict__ indptr, int n) {
  __shared__ int s[1024];
  __shared__ int base_s;
  int tid = threadIdx.x;
  if (tid == 0) { base_s = 0; indptr[0] = 0; }
  __syncthreads();
  for (int c = 0; c < n; c += 1024) {
    int i = c + tid;
    int v = (i < n) ? cnt[i] : 0;
    s[tid] = v;
    __syncthreads();
    for (int off = 1; off < 1024; off <<= 1) {
      int t = (tid >= off) ? s[tid - off] : 0;
      __syncthreads();
      s[tid] += t;
      __syncthreads();
    }
    if (i < n) indptr[i + 1] = base_s + s[tid];
    __syncthreads();
    if (tid == 0) base_s += s[1023];
    __syncthreads();
  }
}

__global__ void copy_int_kernel(const int* __restrict__ a, int* __restrict__ b, int n) {
  int i = blockIdx.x * 256 + threadIdx.x;
  if (i < n) b[i] = a[i];
}

__global__ void fill_kernel(const int* __restrict__ src, const int* __restrict__ dst, int E,
                            int* __restrict__ cursor, int* __restrict__ idx) {
  int e = blockIdx.x * 256 + threadIdx.x;
  if (e < E) {
    int p = atomicAdd(&cursor[dst[e]], 1);
    idx[p] = src[e];
  }
}

// ---------------- wave-per-bucket rank sort (deterministic: sorted by value) ---
__global__ void rank_sort_kernel(const int* __restrict__ indptr, int* __restrict__ idx,
                                 int n) {
  int wv = threadIdx.x >> 6, lane = threadIdx.x & 63;
  int b = blockIdx.x * (blockDim.x >> 6) + wv;
  if (b >= n) return;
  int lo = indptr[b];
  int d = indptr[b + 1] - lo;
  if (d <= 1) return;
  if (d <= 256) {
    int v0 = (lane < d) ? idx[lo + lane] : 0x7fffffff;
    int v1 = (64 + lane < d) ? idx[lo + 64 + lane] : 0x7fffffff;
    int v2 = (128 + lane < d) ? idx[lo + 128 + lane] : 0x7fffffff;
    int v3 = (192 + lane < d) ? idx[lo + 192 + lane] : 0x7fffffff;
    int r0 = 0, r1 = 0, r2 = 0, r3 = 0;
    for (int j = 0; j < d; j++) {
      int q = j >> 6;
      int sel = (q == 0) ? v0 : (q == 1) ? v1 : (q == 2) ? v2 : v3;
      int bj = __shfl(sel, j & 63);
      r0 += (bj < v0 || (bj == v0 && j < lane)) ? 1 : 0;
      r1 += (bj < v1 || (bj == v1 && j < 64 + lane)) ? 1 : 0;
      r2 += (bj < v2 || (bj == v2 && j < 128 + lane)) ? 1 : 0;
      r3 += (bj < v3 || (bj == v3 && j < 192 + lane)) ? 1 : 0;
    }
    if (lane < d) idx[lo + r0] = v0;
    if (64 + lane < d) idx[lo + r1] = v1;
    if (128 + lane < d) idx[lo + r2] = v2;
    if (192 + lane < d) idx[lo + r3] = v3;
  } else if (lane == 0) {
    for (int i = lo + 1; i < lo + d; i++) {
      int v = idx[i];
      int j = i - 1;
      while (j >= lo && idx[j] > v) { idx[j + 1] = idx[j]; j--; }
      idx[j + 1] = v;
    }
  }
}

// ---------------- neighbor mean, XCD-sliced, f16 gather -> f16 out -------------
// thread handles 8 f16 (16B). tprsh = log2(thread-groups per dst row per slice).
// knn: D=4096 -> 512 grp, 64/slice, tprsh=6. genet: D=1024 -> 128 grp, 16/slice,
// tprsh=4. grid (8 slices, rows/rowsPerBlock).
__global__ void agg_slice_f16_kernel(const unsigned short* __restrict__ src,
                                     unsigned short* __restrict__ dh,
                                     const int* __restrict__ indptr,
                                     const int* __restrict__ idx, int D, int tprsh) {
  int tid = threadIdx.x;
  int d = blockIdx.y * (256 >> tprsh) + (tid >> tprsh);
  int k8 = blockIdx.x * (1 << tprsh) + (tid & ((1 << tprsh) - 1));
  int lo = indptr[d], hi = indptr[d + 1];
  float s[8] = {0.f, 0.f, 0.f, 0.f, 0.f, 0.f, 0.f, 0.f};
  for (int j = lo; j < hi; j++) {
    half8 v = ((const half8*)(src + (size_t)idx[j] * D))[k8];
#pragma unroll
    for (int e = 0; e < 8; e++) s[e] += (float)v[e];
  }
  int c = hi - lo;
  float inv = 1.f / (float)(c > 0 ? c : 1);
  half8 o;
#pragma unroll
  for (int e = 0; e < 8; e++) o[e] = (_Float16)(s[e] * inv);
  ((half8*)(dh + (size_t)d * D))[k8] = o;
}

// ---------------- dual f16 MFMA NT GEMM (pure f16, splitK=2, 4 blocks/CU) ------
// Grid 1024: q = swz>>8: product p=q>>1, K-half kh=q&1; P[q] = raw partial.
// 256 thr = 4 waves, 128x128 tile, wave tile 64x64; BK=32.
// LDS 2 buf x {A,B} x 8KB = 32KB -> 4 blocks/CU. STAGE = 4 GLDS -> vmcnt(4).
// Swizzle (verified): 4 slots/row of 16B; physical p holds logical p^((r>>1)&3).
#define GBM 128
#define GBN 128
#define GBK 32

#define GLDS(g, l)                                                             \
  __builtin_amdgcn_global_load_lds(                                            \
      (const __attribute__((address_space(1))) void*)(g),                      \
      (__attribute__((address_space(3))) void*)(l), 16, 0, 0)

#define BAR()                                                                  \
  {                                                                            \
    asm volatile("" ::: "memory");                                             \
    __builtin_amdgcn_s_barrier();                                              \
    asm volatile("" ::: "memory");                                             \
  }

__global__ __launch_bounds__(256, 4) void dual_gemm_kernel(
    const unsigned short* __restrict__ A1, const unsigned short* __restrict__ A2,
    const unsigned short* __restrict__ B1, const unsigned short* __restrict__ B2,
    float* __restrict__ P0, float* __restrict__ P1,
    float* __restrict__ P2, float* __restrict__ P3, int Ktot, int Kblk) {
  __shared__ unsigned short sm[2][2][4096]; // buf x {A,B} x [128][32] f16 = 32KB
  const int tid = threadIdx.x;
  const int lane = tid & 63;
  const int wid = tid >> 6;
  const int wr = wid >> 1, wc = wid & 1;

  const int bid = blockIdx.x;                   // 1024 blocks
  const int swz = (bid & 7) * 128 + (bid >> 3); // XCD-chunked
  const int q = swz >> 8;                       // 0..3
  const int p = q >> 1, kh = q & 1;
  const int tile = swz & 255;                   // 32 m x 8 n
  const int bm0 = (tile >> 3) * GBM;
  const int bn0 = (tile & 7) * GBN;
  const size_t kbase = (size_t)kh * Kblk;

  const unsigned short* A = p ? A2 : A1;
  const unsigned short* B = p ? B2 : B1;

  const int u0 = tid, u1 = tid + 256;
  const int r0 = u0 >> 2, r1 = u1 >> 2;
  const int c0 = ((u0 & 3) ^ ((r0 >> 1) & 3)) * 8;
  const int c1 = ((u1 & 3) ^ ((r1 >> 1) & 3)) * 8;
  const unsigned short* gA0 = A + (size_t)(bm0 + r0) * Ktot + kbase + c0;
  const unsigned short* gA1 = A + (size_t)(bm0 + r1) * Ktot + kbase + c1;
  const unsigned short* gB0 = B + (size_t)(bn0 + r0) * Ktot + kbase + c0;
  const unsigned short* gB1 = B + (size_t)(bn0 + r1) * Ktot + kbase + c1;

#define STAGE(buf)                                                             \
  {                                                                            \
    GLDS(gA0, &sm[buf][0][u0 * 8]); GLDS(gA1, &sm[buf][0][u1 * 8]);            \
    GLDS(gB0, &sm[buf][1][u0 * 8]); GLDS(gB1, &sm[buf][1][u1 * 8]);            \
    gA0 += GBK; gA1 += GBK; gB0 += GBK; gB1 += GBK;                            \
  }

  int offA[4], offB[4];
  {
    int s = lane >> 4;
#pragma unroll
    for (int i = 0; i < 4; i++) {
      int rA = wr * 64 + i * 16 + (lane & 15);
      offA[i] = rA * 32 + ((s ^ ((rA >> 1) & 3)) * 8);
      int rB = wc * 64 + i * 16 + (lane & 15);
      offB[i] = rB * 32 + ((s ^ ((rB >> 1) & 3)) * 8);
    }
  }

  f32x4 acc[4][4];
#pragma unroll
  for (int i = 0; i < 4; i++)
#pragma unroll
    for (int j = 0; j < 4; j++) acc[i][j] = (f32x4)(0.f);

  const int nt = Kblk / GBK; // col: 64, row: 16
  STAGE(0);
  STAGE(1);
  int cur = 0;
  for (int t = 0; t < nt; t++) {
    if (t < nt - 1) {
      asm volatile("s_waitcnt vmcnt(4)" ::: "memory"); // tile t landed
    } else {
      asm volatile("s_waitcnt vmcnt(0)" ::: "memory");
    }
    BAR();
    const unsigned short* smA = &sm[cur][0][0];
    const unsigned short* smB = &sm[cur][1][0];
    half8 av[4], bv[4];
#pragma unroll
    for (int i = 0; i < 4; i++) {
      av[i] = *(const half8*)&smA[offA[i]];
      bv[i] = *(const half8*)&smB[offB[i]];
    }
    __builtin_amdgcn_s_setprio(1);
#pragma unroll
    for (int i = 0; i < 4; i++)
#pragma unroll
      for (int j = 0; j < 4; j++)
        acc[i][j] = __builtin_amdgcn_mfma_f32_16x16x32_f16(av[i], bv[j],
                                                           acc[i][j], 0, 0, 0);
    __builtin_amdgcn_s_setprio(0);
    BAR(); // all waves done reading sm[cur]
    if (t + 2 < nt) STAGE(cur);
    cur ^= 1;
  }

  float* P = q == 0 ? P0 : q == 1 ? P1 : q == 2 ? P2 : P3;
  const int rowq = (lane >> 4) * 4;
  const int colq = lane & 15;
#pragma unroll
  for (int i = 0; i < 4; i++) {
#pragma unroll
    for (int j = 0; j < 4; j++) {
#pragma unroll
      for (int e = 0; e < 4; e++) {
        int row = bm0 + wr * 64 + i * 16 + rowq + e;
        int col = bn0 + wc * 64 + j * 16 + colq;
        P[(size_t)row * 1024 + col] = acc[i][j][e];
      }
    }
  }
}

// ---------------- combine4: E1h = f16(leaky(P0..P3 + bias[row])) ---------------
__global__ void combine_split_kernel(const float* __restrict__ P0, const float* __restrict__ P1,
                                     const float* __restrict__ P2, const float* __restrict__ P3,
                                     const float* __restrict__ bias,
                                     unsigned short* __restrict__ Ch) {
  int i = blockIdx.x * 256 + threadIdx.x; // float4 index, 1M total
  float4 a = ((const float4*)P0)[i];
  float4 b = ((const float4*)P1)[i];
  float4 c = ((const float4*)P2)[i];
  float4 d = ((const float4*)P3)[i];
  float bb = bias[(i * 4) >> 10];
  float4 v;
  v.x = a.x + b.x + c.x + d.x + bb;
  v.y = a.y + b.y + c.y + d.y + bb;
  v.z = a.z + b.z + c.z + d.z + bb;
  v.w = a.w + b.w + c.w + d.w + bb;
  v.x = v.x > 0.f ? v.x : 0.01f * v.x;
  v.y = v.y > 0.f ? v.y : 0.01f * v.y;
  v.z = v.z > 0.f ? v.z : 0.01f * v.z;
  v.w = v.w > 0.f ? v.w : 0.01f * v.w;
  ushort4 h;
  h.x = f2h(v.x); h.y = f2h(v.y); h.z = f2h(v.z); h.w = f2h(v.w);
  ((ushort4*)Ch)[i] = h;
}

// ---------------- combine4: C = leaky(P0..P3 + bias[col]) (fp32 out) -----------
__global__ void combine_kernel(const float* __restrict__ P0, const float* __restrict__ P1,
                               const float* __restrict__ P2, const float* __restrict__ P3,
                               const float* __restrict__ bias, float* __restrict__ C) {
  int i = blockIdx.x * 256 + threadIdx.x;
  float4 a = ((const float4*)P0)[i];
  float4 b = ((const float4*)P1)[i];
  float4 c = ((const float4*)P2)[i];
  float4 d = ((const float4*)P3)[i];
  float4 bb = *(const float4*)(bias + ((i * 4) & 1023));
  float4 v;
  v.x = a.x + b.x + c.x + d.x + bb.x;
  v.y = a.y + b.y + c.y + d.y + bb.y;
  v.z = a.z + b.z + c.z + d.z + bb.z;
  v.w = a.w + b.w + c.w + d.w + bb.w;
  v.x = v.x > 0.f ? v.x : 0.01f * v.x;
  v.y = v.y > 0.f ? v.y : 0.01f * v.y;
  v.z = v.z > 0.f ? v.z : 0.01f * v.z;
  v.w = v.w > 0.f ? v.w : 0.01f * v.w;
  ((float4*)C)[i] = v;
}

extern "C" void kernel_launch(void* const* d_in, const int* in_sizes, int n_in,
                              void* d_out, int out_size, void* d_ws, size_t ws_size,
                              hipStream_t stream) {
  const float* x      = (const float*)d_in[0];
  const float* col_Wl = (const float*)d_in[1];
  const float* col_Wr = (const float*)d_in[2];
  const float* col_b  = (const float*)d_in[3];
  const float* row_Wl = (const float*)d_in[4];
  const float* row_Wr = (const float*)d_in[5];
  const float* row_b  = (const float*)d_in[6];
  const int*   knn    = (const int*)d_in[7];   // [2][KNN_E]
  const int*   genet  = (const int*)d_in[8];   // [2][GENET_E]
  float* out = (float*)d_out;

  const size_t MAT = (size_t)COL_DIM * ROW_DIM; // 4M elements
  const size_t WCOL = (size_t)COL_DIM * COL_DIM;
  const size_t WROW = (size_t)ROW_DIM * ROW_DIM;
  char* w = (char*)d_ws;
  unsigned short* ETh = (unsigned short*)w; w += MAT * 2; // [1024][4096] f16
  unsigned short* Mh  = (unsigned short*)w; w += MAT * 2; // knn mean f16
  unsigned short* Gh  = (unsigned short*)w; w += MAT * 2; // genet mean f16
  unsigned short* E1h = (unsigned short*)w; w += MAT * 2; // [4096][1024] f16
  unsigned short* WH1 = (unsigned short*)w; w += WCOL * 2; // col Wl f16 (32MB)
  unsigned short* WH2 = (unsigned short*)w; w += WCOL * 2; // col Wr f16 (32MB)
  unsigned short* RH1 = (unsigned short*)w; w += WROW * 2; // row Wl f16 (2MB)
  unsigned short* RH2 = (unsigned short*)w; w += WROW * 2; // row Wr f16 (2MB)
  float* PP0 = (float*)w; w += MAT * 4;
  float* PP1 = (float*)w; w += MAT * 4;
  float* PP2 = (float*)w; w += MAT * 4;
  float* PP3 = (float*)w; w += MAT * 4;
  int* kcnt = (int*)w; w += 1024 * 4;
  int* kptr = (int*)w; w += 1025 * 4;
  int* kidx = (int*)w; w += KNN_E * 4;
  int* gcnt = (int*)w; w += 4096 * 4;
  int* gptr = (int*)w; w += 4097 * 4;
  int* gidx = (int*)w; w += (size_t)GENET_E * 4;

  // ---- CSR build (deterministic via per-bucket value sort) ----
  hipMemsetAsync(kcnt, 0, 1024 * 4, stream);
  hipMemsetAsync(gcnt, 0, 4096 * 4, stream);
  count_kernel<<<KNN_E / 256, 256, 0, stream>>>(knn + KNN_E, KNN_E, kcnt);
  count_kernel<<<GENET_E / 256, 256, 0, stream>>>(genet + GENET_E, GENET_E, gcnt);
  scan_kernel<<<1, 1024, 0, stream>>>(kcnt, kptr, 1024);
  scan_kernel<<<1, 1024, 0, stream>>>(gcnt, gptr, 4096);
  copy_int_kernel<<<4, 256, 0, stream>>>(kptr, kcnt, 1024);
  copy_int_kernel<<<16, 256, 0, stream>>>(gptr, gcnt, 4096);
  fill_kernel<<<KNN_E / 256, 256, 0, stream>>>(knn, knn + KNN_E, KNN_E, kcnt, kidx);
  fill_kernel<<<GENET_E / 256, 256, 0, stream>>>(genet, genet + GENET_E, GENET_E, gcnt, gidx);
  rank_sort_kernel<<<256, 256, 0, stream>>>(kptr, kidx, 1024);
  rank_sort_kernel<<<1024, 256, 0, stream>>>(gptr, gidx, 4096);

  const float* Ein = x;
  for (int i = 0; i < NUM_LAYERS; i++) {
    const float* cWl = col_Wl + (size_t)i * WCOL;
    const float* cWr = col_Wr + (size_t)i * WCOL;
    const float* cb  = col_b + (size_t)i * COL_DIM;
    const float* rWl = row_Wl + (size_t)i * WROW;
    const float* rWr = row_Wr + (size_t)i * WROW;
    const float* rb  = row_b + (size_t)i * ROW_DIM;

    // ---- column branch: E1h = f16(leaky(cWl@M^T + cWr@ET^T + cb[row])) ----
    transpose_h_kernel<<<dim3(ROW_DIM / 32, COL_DIM / 32), dim3(32, 8), 0, stream>>>(
        Ein, ETh, COL_DIM, ROW_DIM);
    agg_slice_f16_kernel<<<dim3(8, 256), 256, 0, stream>>>(ETh, Mh, kptr, kidx,
                                                           COL_DIM, 6);
    split_f16_kernel<<<2048, 256, 0, stream>>>(cWl, WH1, (int)(WCOL / 4));
    split_f16_kernel<<<2048, 256, 0, stream>>>(cWr, WH2, (int)(WCOL / 4));
    dual_gemm_kernel<<<1024, 256, 0, stream>>>(
        WH1, WH2, Mh, ETh, PP0, PP1, PP2, PP3, COL_DIM, COL_DIM / 2);
    combine_split_kernel<<<4096, 256, 0, stream>>>(PP0, PP1, PP2, PP3, cb, E1h);

    // ---- row branch: out = leaky(G@rWl^T + E1@rWr^T + rb[col]) ----
    agg_slice_f16_kernel<<<dim3(8, 256), 256, 0, stream>>>(E1h, Gh, gptr, gidx,
                                                           ROW_DIM, 4);
    split_f16_kernel<<<1024, 256, 0, stream>>>(rWl, RH1, (int)(WROW / 4));
    split_f16_kernel<<<1024, 256, 0, stream>>>(rWr, RH2, (int)(WROW / 4));
    dual_gemm_kernel<<<1024, 256, 0, stream>>>(
        Gh, E1h, RH1, RH2, PP0, PP1, PP2, PP3, ROW_DIM, ROW_DIM / 2);
    combine_kernel<<<4096, 256, 0, stream>>>(PP0, PP1, PP2, PP3, rb, out);

    Ein = out;
  }
}